// Round 15
// baseline (441.835 us; speedup 1.0000x reference)
//
#include <hip/hip_runtime.h>
#include <hip/hip_bf16.h>
#include <hip/hip_fp16.h>

// 5-layer GCN: out = relu( D^-1/2 (A+I) D^-1/2 (x W_l) + b_l ), x5.
// N=50000, E=800000, D=128.
//
// R15: gemm occupancy fix. R14's 128-row blocks gave only 391 blocks on
// 256 CUs (1.5 blocks/CU, 6 waves/CU) -> latency-bound at ~22us vs ~9us
// floor. Now 64 rows/block (782 blocks, ~3 blocks/CU, 12 waves/CU),
// 1 m-tile per wave, t-tiles processed in PAIRS (2 independent MFMA acc
// chains per wave for ILP). W staged in two 32KB halves as before (reads
// double to 50MB but L2-hit). init_kernel -> hipMemsetAsync (one fewer
// dispatch). agg frozen at R12/R14 form (46us = structural floor).

#define GCN_DIM 128

typedef short bf16x8 __attribute__((ext_vector_type(8)));
typedef float f32x4 __attribute__((ext_vector_type(4)));

__device__ __forceinline__ unsigned short f2bf(float f) {
    unsigned int u = __float_as_uint(f);
    u += 0x7FFFu + ((u >> 16) & 1u);  // RTNE
    return (unsigned short)(u >> 16);
}
__device__ __forceinline__ float bf2f(unsigned short b) {
    return __uint_as_float(((unsigned int)b) << 16);
}
__device__ __forceinline__ float bflo(unsigned int p) { return __uint_as_float(p << 16); }
__device__ __forceinline__ float bfhi(unsigned int p) { return __uint_as_float(p & 0xFFFF0000u); }

// count + capture per-edge rank (old value of the atomic)
__global__ void count_kernel(const int* __restrict__ dst, int* __restrict__ cnt,
                             int* __restrict__ rank, int E) {
    int e = blockIdx.x * 256 + threadIdx.x;
    if (e < E) rank[e] = atomicAdd(&cnt[dst[e]], 1);
}

// ---- hierarchical scan ----
__global__ __launch_bounds__(256) void scan_part_kernel(const int* __restrict__ cnt,
                                                        int* __restrict__ loc,
                                                        int* __restrict__ bsum, int n) {
    __shared__ int s[256];
    int t = threadIdx.x;
    int i0 = blockIdx.x * 1024 + t * 4;
    int v0 = (i0 + 0 < n) ? cnt[i0 + 0] : 0;
    int v1 = (i0 + 1 < n) ? cnt[i0 + 1] : 0;
    int v2 = (i0 + 2 < n) ? cnt[i0 + 2] : 0;
    int v3 = (i0 + 3 < n) ? cnt[i0 + 3] : 0;
    int tsum = v0 + v1 + v2 + v3;
    s[t] = tsum;
    __syncthreads();
    for (int d = 1; d < 256; d <<= 1) {
        int u = (t >= d) ? s[t - d] : 0;
        __syncthreads();
        s[t] += u;
        __syncthreads();
    }
    int base = s[t] - tsum;
    if (i0 + 0 < n) loc[i0 + 0] = base; base += v0;
    if (i0 + 1 < n) loc[i0 + 1] = base; base += v1;
    if (i0 + 2 < n) loc[i0 + 2] = base; base += v2;
    if (i0 + 3 < n) loc[i0 + 3] = base;
    if (t == 255) bsum[blockIdx.x] = s[255];
}

__global__ __launch_bounds__(256) void scan_top_kernel(int* __restrict__ bsum, int nb) {
    __shared__ int s[256];
    int t = threadIdx.x;
    int v = (t < nb) ? bsum[t] : 0;
    s[t] = v;
    __syncthreads();
    for (int d = 1; d < 256; d <<= 1) {
        int u = (t >= d) ? s[t - d] : 0;
        __syncthreads();
        s[t] += u;
        __syncthreads();
    }
    if (t < nb) bsum[t] = s[t] - v;
}

// scan finalize + dinv (folded)
__global__ void scan_add_kernel(int* __restrict__ offs,
                                const int* __restrict__ bsum, const int* __restrict__ cnt,
                                float* __restrict__ dinv, int n, int E) {
    int i = blockIdx.x * 256 + threadIdx.x;
    if (i < n) {
        offs[i] = offs[i] + bsum[i >> 10];
        dinv[i] = rsqrtf((float)cnt[i] + 1.0f);
    }
    if (i == 0) offs[n] = E;
}

// CSR fill, atomic-free: p = offs[dst] + rank[e].
// Packed (src | fp16(dinv[src])<<16).
__global__ void fill_kernel(const int* __restrict__ src, const int* __restrict__ dst,
                            const float* __restrict__ dinv, const int* __restrict__ rank,
                            const int* __restrict__ offs,
                            unsigned int* __restrict__ edat, int E) {
    int e = blockIdx.x * 256 + threadIdx.x;
    if (e < E) {
        int d = dst[e];
        int s = src[e];
        int p = offs[d] + rank[e];
        unsigned short wb = __half_as_ushort(__float2half(dinv[s]));
        edat[p] = (unsigned int)s | ((unsigned int)wb << 16);
    }
}

// x0 fp32 -> (xh, xl) bf16 pair.
__global__ void split_x_kernel(const float* __restrict__ x, unsigned short* __restrict__ xh,
                               unsigned short* __restrict__ xl, int total) {
    int i = (blockIdx.x * 256 + threadIdx.x) * 4;
    if (i >= total) return;
    float4 v = *(const float4*)&x[i];
    ushort4 h4, l4;
    h4.x = f2bf(v.x); l4.x = f2bf(v.x - bf2f(h4.x));
    h4.y = f2bf(v.y); l4.y = f2bf(v.y - bf2f(h4.y));
    h4.z = f2bf(v.z); l4.z = f2bf(v.z - bf2f(h4.z));
    h4.w = f2bf(v.w); l4.w = f2bf(v.w - bf2f(h4.w));
    *(ushort4*)&xh[i] = h4;
    *(ushort4*)&xl[i] = l4;
}

// W [l][k][n] fp32 -> Wfh/Wfl in MFMA fragment order:
// group g = l*32 + t*4 + ks; elem = ((g*64) + q*16+ln)*8 + j
// holds W^T[t*16+ln][ks*32+q*8+j].  (Used as the A operand.)
__global__ void wsplit_kernel(const float* __restrict__ Wall, unsigned short* __restrict__ Wfh,
                              unsigned short* __restrict__ Wfl, int total) {
    int idx = blockIdx.x * 256 + threadIdx.x;
    if (idx >= total) return;
    int l = idx >> 14;
    int rem = idx & 16383;
    int k = rem >> 7;
    int nn = rem & 127;
    float v = Wall[idx];
    unsigned short hi = f2bf(v);
    unsigned short lo = f2bf(v - bf2f(hi));
    int t = nn >> 4, ln = nn & 15;
    int ks = k >> 5, q = (k >> 3) & 3, j = k & 7;
    int o = ((((l << 5) | (t << 2) | ks) << 6) | (q << 4) | ln) * 8 + j;
    Wfh[o] = hi;
    Wfl[o] = lo;
}

// MFMA GEMM: h = (xh+xl) @ (Wh+Wl), bf16 store. 64 rows/block (782 blocks,
// ~3 blocks/CU), 4 waves x 1 m-tile. t-tiles in pairs -> 2 independent acc
// chains per wave. Operands swapped (A=W frag, B=x frag) so each lane
// packs 4 consecutive cols of one node row into one 8B store.
__global__ __launch_bounds__(256) void gemm_mfma_kernel(
    const unsigned short* __restrict__ xh, const unsigned short* __restrict__ xl,
    const unsigned short* __restrict__ Wfh, const unsigned short* __restrict__ Wfl,
    unsigned short* __restrict__ h, int n) {
    __shared__ unsigned short ldsW[2][8192];  // 16KB hi + 16KB lo
    int tid = threadIdx.x;
    int wave = tid >> 6, lane = tid & 63;
    int q = lane >> 4, ln = lane & 15;
    int rowbase = blockIdx.x * 64 + wave * 16;
    bf16x8 A[4][2];  // x fragments (B operand): [ks][hi/lo]
    {
        int ar = rowbase + ln;
        if (ar >= n) ar = n - 1;
        size_t base = (size_t)ar * GCN_DIM;
#pragma unroll
        for (int ks = 0; ks < 4; ks++) {
            A[ks][0] = *(const bf16x8*)&xh[base + ks * 32 + q * 8];
            A[ks][1] = *(const bf16x8*)&xl[base + ks * 32 + q * 8];
        }
    }
    int node = rowbase + ln;
#pragma unroll
    for (int half = 0; half < 2; half++) {
        if (half) __syncthreads();  // wait for previous half's compute
        {
            const uint4* gh = (const uint4*)(Wfh + half * 8192);
            const uint4* gl = (const uint4*)(Wfl + half * 8192);
            uint4* sh = (uint4*)ldsW[0];
            uint4* sl = (uint4*)ldsW[1];
#pragma unroll
            for (int r = 0; r < 4; r++) {
                sh[tid + 256 * r] = gh[tid + 256 * r];
                sl[tid + 256 * r] = gl[tid + 256 * r];
            }
        }
        __syncthreads();
#pragma unroll
        for (int tp = 0; tp < 2; tp++) {  // t-pair: tt_a = tp*2, tt_b = tp*2+1
            int tta = tp * 2, ttb = tp * 2 + 1;
            f32x4 accA = (f32x4)(0.f), accB = (f32x4)(0.f);
#pragma unroll
            for (int ks = 0; ks < 4; ks++) {
                int foA = ((tta * 4 + ks) * 64 + lane) * 8;
                int foB = ((ttb * 4 + ks) * 64 + lane) * 8;
                bf16x8 bhA = *(const bf16x8*)&ldsW[0][foA];
                bf16x8 blA = *(const bf16x8*)&ldsW[1][foA];
                bf16x8 bhB = *(const bf16x8*)&ldsW[0][foB];
                bf16x8 blB = *(const bf16x8*)&ldsW[1][foB];
                accA = __builtin_amdgcn_mfma_f32_16x16x32_bf16(bhA, A[ks][0], accA, 0, 0, 0);
                accB = __builtin_amdgcn_mfma_f32_16x16x32_bf16(bhB, A[ks][0], accB, 0, 0, 0);
                accA = __builtin_amdgcn_mfma_f32_16x16x32_bf16(bhA, A[ks][1], accA, 0, 0, 0);
                accB = __builtin_amdgcn_mfma_f32_16x16x32_bf16(bhB, A[ks][1], accB, 0, 0, 0);
                accA = __builtin_amdgcn_mfma_f32_16x16x32_bf16(blA, A[ks][0], accA, 0, 0, 0);
                accB = __builtin_amdgcn_mfma_f32_16x16x32_bf16(blB, A[ks][0], accB, 0, 0, 0);
            }
            if (node < n) {
                int ta = half * 4 + tta, tb = half * 4 + ttb;
                ushort4 oA, oB;
                oA.x = f2bf(accA[0]); oA.y = f2bf(accA[1]);
                oA.z = f2bf(accA[2]); oA.w = f2bf(accA[3]);
                oB.x = f2bf(accB[0]); oB.y = f2bf(accB[1]);
                oB.z = f2bf(accB[2]); oB.w = f2bf(accB[3]);
                *(ushort4*)&h[(size_t)node * GCN_DIM + ta * 16 + q * 4] = oA;
                *(ushort4*)&h[(size_t)node * GCN_DIM + tb * 16 + q * 4] = oB;
            }
        }
    }
}

// Sliced aggregation (R12 form, frozen): block = 16 nodes x one 32-feature
// slice (slice = blockIdx&3). Wave = 4 nodes x 16 lanes x 2 feats. Unroll
// x8, 4 acc pairs. fp16 weight in edat upper bits. edat cached; outputs nt.
__global__ __launch_bounds__(256) void agg_kernel(
    const unsigned short* __restrict__ h,
    const unsigned int* __restrict__ edat,
    const int* __restrict__ offs,
    const float* __restrict__ dinv, const float* __restrict__ bias,
    unsigned short* __restrict__ xh_out,
    unsigned short* __restrict__ xl_out,
    float* __restrict__ fout, int n) {
    int tid = threadIdx.x;
    int wave = tid >> 6, lane = tid & 63;
    int sub = lane >> 4, ln = lane & 15;
    int slice = blockIdx.x & 3;
    int node = (blockIdx.x >> 2) * 16 + wave * 4 + sub;
    if (node >= n) return;
    int co = slice * 32 + ln * 2;  // this lane's 2 features
    float di = dinv[node];
    unsigned int sp = *(const unsigned int*)&h[((size_t)node << 7) + co];
    float ax0 = di * bflo(sp), ay0 = di * bfhi(sp);
    float ax1 = 0.f, ay1 = 0.f, ax2 = 0.f, ay2 = 0.f, ax3 = 0.f, ay3 = 0.f;
    int s = offs[node], e = offs[node + 1];
    int j = s;
    for (; j + 8 <= e; j += 8) {
        unsigned int v0 = edat[j], v1 = edat[j + 1], v2 = edat[j + 2], v3 = edat[j + 3];
        unsigned int v4 = edat[j + 4], v5 = edat[j + 5], v6 = edat[j + 6], v7 = edat[j + 7];
        unsigned int p0 = *(const unsigned int*)&h[((size_t)(v0 & 0xFFFFu) << 7) + co];
        unsigned int p1 = *(const unsigned int*)&h[((size_t)(v1 & 0xFFFFu) << 7) + co];
        unsigned int p2 = *(const unsigned int*)&h[((size_t)(v2 & 0xFFFFu) << 7) + co];
        unsigned int p3 = *(const unsigned int*)&h[((size_t)(v3 & 0xFFFFu) << 7) + co];
        unsigned int p4 = *(const unsigned int*)&h[((size_t)(v4 & 0xFFFFu) << 7) + co];
        unsigned int p5 = *(const unsigned int*)&h[((size_t)(v5 & 0xFFFFu) << 7) + co];
        unsigned int p6 = *(const unsigned int*)&h[((size_t)(v6 & 0xFFFFu) << 7) + co];
        unsigned int p7 = *(const unsigned int*)&h[((size_t)(v7 & 0xFFFFu) << 7) + co];
        float w0 = __half2float(__ushort_as_half((unsigned short)(v0 >> 16)));
        float w1 = __half2float(__ushort_as_half((unsigned short)(v1 >> 16)));
        float w2 = __half2float(__ushort_as_half((unsigned short)(v2 >> 16)));
        float w3 = __half2float(__ushort_as_half((unsigned short)(v3 >> 16)));
        float w4 = __half2float(__ushort_as_half((unsigned short)(v4 >> 16)));
        float w5 = __half2float(__ushort_as_half((unsigned short)(v5 >> 16)));
        float w6 = __half2float(__ushort_as_half((unsigned short)(v6 >> 16)));
        float w7 = __half2float(__ushort_as_half((unsigned short)(v7 >> 16)));
        ax0 = fmaf(w0, bflo(p0), ax0); ay0 = fmaf(w0, bfhi(p0), ay0);
        ax1 = fmaf(w1, bflo(p1), ax1); ay1 = fmaf(w1, bfhi(p1), ay1);
        ax2 = fmaf(w2, bflo(p2), ax2); ay2 = fmaf(w2, bfhi(p2), ay2);
        ax3 = fmaf(w3, bflo(p3), ax3); ay3 = fmaf(w3, bfhi(p3), ay3);
        ax0 = fmaf(w4, bflo(p4), ax0); ay0 = fmaf(w4, bfhi(p4), ay0);
        ax1 = fmaf(w5, bflo(p5), ax1); ay1 = fmaf(w5, bfhi(p5), ay1);
        ax2 = fmaf(w6, bflo(p6), ax2); ay2 = fmaf(w6, bfhi(p6), ay2);
        ax3 = fmaf(w7, bflo(p7), ax3); ay3 = fmaf(w7, bfhi(p7), ay3);
    }
    for (; j + 4 <= e; j += 4) {
        unsigned int v0 = edat[j], v1 = edat[j + 1], v2 = edat[j + 2], v3 = edat[j + 3];
        unsigned int p0 = *(const unsigned int*)&h[((size_t)(v0 & 0xFFFFu) << 7) + co];
        unsigned int p1 = *(const unsigned int*)&h[((size_t)(v1 & 0xFFFFu) << 7) + co];
        unsigned int p2 = *(const unsigned int*)&h[((size_t)(v2 & 0xFFFFu) << 7) + co];
        unsigned int p3 = *(const unsigned int*)&h[((size_t)(v3 & 0xFFFFu) << 7) + co];
        float w0 = __half2float(__ushort_as_half((unsigned short)(v0 >> 16)));
        float w1 = __half2float(__ushort_as_half((unsigned short)(v1 >> 16)));
        float w2 = __half2float(__ushort_as_half((unsigned short)(v2 >> 16)));
        float w3 = __half2float(__ushort_as_half((unsigned short)(v3 >> 16)));
        ax0 = fmaf(w0, bflo(p0), ax0); ay0 = fmaf(w0, bfhi(p0), ay0);
        ax1 = fmaf(w1, bflo(p1), ax1); ay1 = fmaf(w1, bfhi(p1), ay1);
        ax2 = fmaf(w2, bflo(p2), ax2); ay2 = fmaf(w2, bfhi(p2), ay2);
        ax3 = fmaf(w3, bflo(p3), ax3); ay3 = fmaf(w3, bfhi(p3), ay3);
    }
    for (; j < e; j++) {
        unsigned int v0 = edat[j];
        unsigned int p0 = *(const unsigned int*)&h[((size_t)(v0 & 0xFFFFu) << 7) + co];
        float w0 = __half2float(__ushort_as_half((unsigned short)(v0 >> 16)));
        ax0 = fmaf(w0, bflo(p0), ax0);
        ay0 = fmaf(w0, bfhi(p0), ay0);
    }
    float ax = (ax0 + ax1) + (ax2 + ax3);
    float ay = (ay0 + ay1) + (ay2 + ay3);
    float2 b = *(const float2*)&bias[co];
    float rx = fmaxf(fmaf(di, ax, b.x), 0.f);
    float ry = fmaxf(fmaf(di, ay, b.y), 0.f);
    if (fout) {
        unsigned long long pv = (unsigned long long)__float_as_uint(rx) |
                                ((unsigned long long)__float_as_uint(ry) << 32);
        __builtin_nontemporal_store(pv, (unsigned long long*)&fout[((size_t)node << 7) + co]);
    } else {
        unsigned short hx = f2bf(rx), hy = f2bf(ry);
        unsigned int hp = (unsigned int)hx | ((unsigned int)hy << 16);
        unsigned short lx = f2bf(rx - bf2f(hx)), ly = f2bf(ry - bf2f(hy));
        unsigned int lp = (unsigned int)lx | ((unsigned int)ly << 16);
        __builtin_nontemporal_store(hp, (unsigned int*)&xh_out[((size_t)node << 7) + co]);
        __builtin_nontemporal_store(lp, (unsigned int*)&xl_out[((size_t)node << 7) + co]);
    }
}

extern "C" void kernel_launch(void* const* d_in, const int* in_sizes, int n_in,
                              void* d_out, int out_size, void* d_ws, size_t ws_size,
                              hipStream_t stream) {
    const float* x0    = (const float*)d_in[0];
    const int*   edges = (const int*)d_in[1];   // [2, E] int32: src then dst
    const float* Wall  = (const float*)d_in[2]; // [L, 128, 128]
    const float* Ball  = (const float*)d_in[3]; // [L, 128]
    float* out = (float*)d_out;

    const int n = in_sizes[0] / GCN_DIM;              // 50000
    const int E = in_sizes[1] / 2;                    // 800000
    const int L = in_sizes[2] / (GCN_DIM * GCN_DIM);  // 5

    // workspace layout
    int*   cnt    = (int*)d_ws;                        // n
    float* dinv   = (float*)(cnt + n);                 // n
    int*   offs   = (int*)(dinv + n);                  // n+16
    int*   bsum   = offs + n + 16;                     // 64
    int*   rank   = bsum + 64;                         // E
    unsigned int* edat = (unsigned int*)(rank + E);    // E (4B each)
    unsigned short* h   = (unsigned short*)(edat + E); // n*128 bf16
    unsigned short* xh  = h  + (size_t)n * GCN_DIM;    // n*128 bf16
    unsigned short* xl  = xh + (size_t)n * GCN_DIM;    // n*128 bf16
    unsigned short* Wfh = xl + (size_t)n * GCN_DIM;    // L*16384 bf16 frag-order
    unsigned short* Wfl = Wfh + (size_t)L * GCN_DIM * GCN_DIM;

    const int* src = edges;
    const int* dst = edges + E;

    int nb_n = (n + 255) / 256;
    int nb_e = (E + 255) / 256;
    int nb_scan = (n + 1023) / 1024;

    hipMemsetAsync(cnt, 0, (size_t)n * sizeof(int), stream);
    count_kernel<<<nb_e, 256, 0, stream>>>(dst, cnt, rank, E);
    scan_part_kernel<<<nb_scan, 256, 0, stream>>>(cnt, offs, bsum, n);
    scan_top_kernel<<<1, 256, 0, stream>>>(bsum, nb_scan);
    scan_add_kernel<<<nb_n, 256, 0, stream>>>(offs, bsum, cnt, dinv, n, E);
    fill_kernel<<<nb_e, 256, 0, stream>>>(src, dst, dinv, rank, offs, edat, E);

    int xtotal = n * GCN_DIM;
    split_x_kernel<<<(xtotal / 4 + 255) / 256, 256, 0, stream>>>(x0, xh, xl, xtotal);
    int wtotal = L * GCN_DIM * GCN_DIM;
    wsplit_kernel<<<(wtotal + 255) / 256, 256, 0, stream>>>(Wall, Wfh, Wfl, wtotal);

    int gemm_blocks = (n + 63) / 64;
    int agg_blocks  = ((n + 15) / 16) * 4;  // 16 nodes x 4 slices per block

    for (int l = 0; l < L; l++) {
        gemm_mfma_kernel<<<gemm_blocks, 256, 0, stream>>>(
            xh, xl, Wfh + (size_t)l * GCN_DIM * GCN_DIM, Wfl + (size_t)l * GCN_DIM * GCN_DIM, h, n);
        agg_kernel<<<agg_blocks, 256, 0, stream>>>(
            h, edat, offs, dinv, Ball + (size_t)l * GCN_DIM,
            xh, xl, (l == L - 1) ? out : nullptr, n);
    }
}

// Round 16
// 414.250 us; speedup vs baseline: 1.0666x; 1.0666x over previous
//
#include <hip/hip_runtime.h>
#include <hip/hip_bf16.h>
#include <hip/hip_fp16.h>

// 5-layer GCN: out = relu( D^-1/2 (A+I) D^-1/2 (x W_l) + b_l ), x5.
// N=50000, E=800000, D=128.
//
// R16: 8 slices x 16 features, SLICE-MAJOR h layout h[slice][node][16].
// R13 proved slice->XCD mapping wasn't the problem; capacity was (3.2MB
// slice + streams > 4MB L2 -> ~50% hit, FETCH 103MB vs 40MB floor).
// Slice-major makes a 16-feature slice CONTIGUOUS 1.6MB (row-major would
// still touch 3.2MB of 64B lines). gemm tile t == slice t, so the store
// is h[(t*N+node)*16+q*4], 8B/lane, wave-contiguous 512B. agg: wave =
// 8 nodes x 8 lanes, 32B gather/edge, slice = blockIdx&7. edat stream
// x8 = 25.6MB/layer (~9us, cheap). Everything else frozen at R15.

#define GCN_DIM 128

typedef short bf16x8 __attribute__((ext_vector_type(8)));
typedef float f32x4 __attribute__((ext_vector_type(4)));

__device__ __forceinline__ unsigned short f2bf(float f) {
    unsigned int u = __float_as_uint(f);
    u += 0x7FFFu + ((u >> 16) & 1u);  // RTNE
    return (unsigned short)(u >> 16);
}
__device__ __forceinline__ float bf2f(unsigned short b) {
    return __uint_as_float(((unsigned int)b) << 16);
}
__device__ __forceinline__ float bflo(unsigned int p) { return __uint_as_float(p << 16); }
__device__ __forceinline__ float bfhi(unsigned int p) { return __uint_as_float(p & 0xFFFF0000u); }

// count + capture per-edge rank (old value of the atomic)
__global__ void count_kernel(const int* __restrict__ dst, int* __restrict__ cnt,
                             int* __restrict__ rank, int E) {
    int e = blockIdx.x * 256 + threadIdx.x;
    if (e < E) rank[e] = atomicAdd(&cnt[dst[e]], 1);
}

// ---- hierarchical scan ----
__global__ __launch_bounds__(256) void scan_part_kernel(const int* __restrict__ cnt,
                                                        int* __restrict__ loc,
                                                        int* __restrict__ bsum, int n) {
    __shared__ int s[256];
    int t = threadIdx.x;
    int i0 = blockIdx.x * 1024 + t * 4;
    int v0 = (i0 + 0 < n) ? cnt[i0 + 0] : 0;
    int v1 = (i0 + 1 < n) ? cnt[i0 + 1] : 0;
    int v2 = (i0 + 2 < n) ? cnt[i0 + 2] : 0;
    int v3 = (i0 + 3 < n) ? cnt[i0 + 3] : 0;
    int tsum = v0 + v1 + v2 + v3;
    s[t] = tsum;
    __syncthreads();
    for (int d = 1; d < 256; d <<= 1) {
        int u = (t >= d) ? s[t - d] : 0;
        __syncthreads();
        s[t] += u;
        __syncthreads();
    }
    int base = s[t] - tsum;
    if (i0 + 0 < n) loc[i0 + 0] = base; base += v0;
    if (i0 + 1 < n) loc[i0 + 1] = base; base += v1;
    if (i0 + 2 < n) loc[i0 + 2] = base; base += v2;
    if (i0 + 3 < n) loc[i0 + 3] = base;
    if (t == 255) bsum[blockIdx.x] = s[255];
}

__global__ __launch_bounds__(256) void scan_top_kernel(int* __restrict__ bsum, int nb) {
    __shared__ int s[256];
    int t = threadIdx.x;
    int v = (t < nb) ? bsum[t] : 0;
    s[t] = v;
    __syncthreads();
    for (int d = 1; d < 256; d <<= 1) {
        int u = (t >= d) ? s[t - d] : 0;
        __syncthreads();
        s[t] += u;
        __syncthreads();
    }
    if (t < nb) bsum[t] = s[t] - v;
}

// scan finalize + dinv (folded)
__global__ void scan_add_kernel(int* __restrict__ offs,
                                const int* __restrict__ bsum, const int* __restrict__ cnt,
                                float* __restrict__ dinv, int n, int E) {
    int i = blockIdx.x * 256 + threadIdx.x;
    if (i < n) {
        offs[i] = offs[i] + bsum[i >> 10];
        dinv[i] = rsqrtf((float)cnt[i] + 1.0f);
    }
    if (i == 0) offs[n] = E;
}

// CSR fill, atomic-free: p = offs[dst] + rank[e].
// Packed (src | fp16(dinv[src])<<16).
__global__ void fill_kernel(const int* __restrict__ src, const int* __restrict__ dst,
                            const float* __restrict__ dinv, const int* __restrict__ rank,
                            const int* __restrict__ offs,
                            unsigned int* __restrict__ edat, int E) {
    int e = blockIdx.x * 256 + threadIdx.x;
    if (e < E) {
        int d = dst[e];
        int s = src[e];
        int p = offs[d] + rank[e];
        unsigned short wb = __half_as_ushort(__float2half(dinv[s]));
        edat[p] = (unsigned int)s | ((unsigned int)wb << 16);
    }
}

// x0 fp32 -> (xh, xl) bf16 pair.
__global__ void split_x_kernel(const float* __restrict__ x, unsigned short* __restrict__ xh,
                               unsigned short* __restrict__ xl, int total) {
    int i = (blockIdx.x * 256 + threadIdx.x) * 4;
    if (i >= total) return;
    float4 v = *(const float4*)&x[i];
    ushort4 h4, l4;
    h4.x = f2bf(v.x); l4.x = f2bf(v.x - bf2f(h4.x));
    h4.y = f2bf(v.y); l4.y = f2bf(v.y - bf2f(h4.y));
    h4.z = f2bf(v.z); l4.z = f2bf(v.z - bf2f(h4.z));
    h4.w = f2bf(v.w); l4.w = f2bf(v.w - bf2f(h4.w));
    *(ushort4*)&xh[i] = h4;
    *(ushort4*)&xl[i] = l4;
}

// W [l][k][n] fp32 -> Wfh/Wfl in MFMA fragment order:
// group g = l*32 + t*4 + ks; elem = ((g*64) + q*16+ln)*8 + j
// holds W^T[t*16+ln][ks*32+q*8+j].  (Used as the A operand.)
__global__ void wsplit_kernel(const float* __restrict__ Wall, unsigned short* __restrict__ Wfh,
                              unsigned short* __restrict__ Wfl, int total) {
    int idx = blockIdx.x * 256 + threadIdx.x;
    if (idx >= total) return;
    int l = idx >> 14;
    int rem = idx & 16383;
    int k = rem >> 7;
    int nn = rem & 127;
    float v = Wall[idx];
    unsigned short hi = f2bf(v);
    unsigned short lo = f2bf(v - bf2f(hi));
    int t = nn >> 4, ln = nn & 15;
    int ks = k >> 5, q = (k >> 3) & 3, j = k & 7;
    int o = ((((l << 5) | (t << 2) | ks) << 6) | (q << 4) | ln) * 8 + j;
    Wfh[o] = hi;
    Wfl[o] = lo;
}

// MFMA GEMM: h = (xh+xl) @ (Wh+Wl), bf16 SLICE-MAJOR store
// h[(t*N + node)*16 + q*4]. 64 rows/block, 4 waves x 1 m-tile, t-pairs.
__global__ __launch_bounds__(256) void gemm_mfma_kernel(
    const unsigned short* __restrict__ xh, const unsigned short* __restrict__ xl,
    const unsigned short* __restrict__ Wfh, const unsigned short* __restrict__ Wfl,
    unsigned short* __restrict__ h, int n) {
    __shared__ unsigned short ldsW[2][8192];  // 16KB hi + 16KB lo
    int tid = threadIdx.x;
    int wave = tid >> 6, lane = tid & 63;
    int q = lane >> 4, ln = lane & 15;
    int rowbase = blockIdx.x * 64 + wave * 16;
    bf16x8 A[4][2];  // x fragments (B operand): [ks][hi/lo]
    {
        int ar = rowbase + ln;
        if (ar >= n) ar = n - 1;
        size_t base = (size_t)ar * GCN_DIM;
#pragma unroll
        for (int ks = 0; ks < 4; ks++) {
            A[ks][0] = *(const bf16x8*)&xh[base + ks * 32 + q * 8];
            A[ks][1] = *(const bf16x8*)&xl[base + ks * 32 + q * 8];
        }
    }
    int node = rowbase + ln;
#pragma unroll
    for (int half = 0; half < 2; half++) {
        if (half) __syncthreads();  // wait for previous half's compute
        {
            const uint4* gh = (const uint4*)(Wfh + half * 8192);
            const uint4* gl = (const uint4*)(Wfl + half * 8192);
            uint4* sh = (uint4*)ldsW[0];
            uint4* sl = (uint4*)ldsW[1];
#pragma unroll
            for (int r = 0; r < 4; r++) {
                sh[tid + 256 * r] = gh[tid + 256 * r];
                sl[tid + 256 * r] = gl[tid + 256 * r];
            }
        }
        __syncthreads();
#pragma unroll
        for (int tp = 0; tp < 2; tp++) {  // t-pair: tt_a = tp*2, tt_b = tp*2+1
            int tta = tp * 2, ttb = tp * 2 + 1;
            f32x4 accA = (f32x4)(0.f), accB = (f32x4)(0.f);
#pragma unroll
            for (int ks = 0; ks < 4; ks++) {
                int foA = ((tta * 4 + ks) * 64 + lane) * 8;
                int foB = ((ttb * 4 + ks) * 64 + lane) * 8;
                bf16x8 bhA = *(const bf16x8*)&ldsW[0][foA];
                bf16x8 blA = *(const bf16x8*)&ldsW[1][foA];
                bf16x8 bhB = *(const bf16x8*)&ldsW[0][foB];
                bf16x8 blB = *(const bf16x8*)&ldsW[1][foB];
                accA = __builtin_amdgcn_mfma_f32_16x16x32_bf16(bhA, A[ks][0], accA, 0, 0, 0);
                accB = __builtin_amdgcn_mfma_f32_16x16x32_bf16(bhB, A[ks][0], accB, 0, 0, 0);
                accA = __builtin_amdgcn_mfma_f32_16x16x32_bf16(bhA, A[ks][1], accA, 0, 0, 0);
                accB = __builtin_amdgcn_mfma_f32_16x16x32_bf16(bhB, A[ks][1], accB, 0, 0, 0);
                accA = __builtin_amdgcn_mfma_f32_16x16x32_bf16(blA, A[ks][0], accA, 0, 0, 0);
                accB = __builtin_amdgcn_mfma_f32_16x16x32_bf16(blB, A[ks][0], accB, 0, 0, 0);
            }
            if (node < n) {
                int ta = half * 4 + tta, tb = half * 4 + ttb;
                ushort4 oA, oB;
                oA.x = f2bf(accA[0]); oA.y = f2bf(accA[1]);
                oA.z = f2bf(accA[2]); oA.w = f2bf(accA[3]);
                oB.x = f2bf(accB[0]); oB.y = f2bf(accB[1]);
                oB.z = f2bf(accB[2]); oB.w = f2bf(accB[3]);
                *(ushort4*)&h[((size_t)ta * n + node) * 16 + q * 4] = oA;
                *(ushort4*)&h[((size_t)tb * n + node) * 16 + q * 4] = oB;
            }
        }
    }
}

// Sliced aggregation: 8 slices x 16 feats, slice-major h. Block = 32 nodes
// x one slice (slice = blockIdx&7 -> one slice per XCD under round-robin;
// 1.6MB contiguous resident set). Wave = 8 nodes x 8 lanes x 2 feats;
// gather = 32B contiguous per edge. Unroll x8, 4 acc pairs. fp16 weight.
// edat cached (single-touch-per-XCD but line-sequential); outputs nt.
__global__ __launch_bounds__(256) void agg_kernel(
    const unsigned short* __restrict__ h,
    const unsigned int* __restrict__ edat,
    const int* __restrict__ offs,
    const float* __restrict__ dinv, const float* __restrict__ bias,
    unsigned short* __restrict__ xh_out,
    unsigned short* __restrict__ xl_out,
    float* __restrict__ fout, int n) {
    int tid = threadIdx.x;
    int wave = tid >> 6, lane = tid & 63;
    int sub = lane >> 3, ln = lane & 7;
    int slice = blockIdx.x & 7;
    int node = (blockIdx.x >> 3) * 32 + wave * 8 + sub;
    if (node >= n) return;
    size_t sbase = (size_t)slice * n;  // slice-major base (in 16-elem rows)
    int fo = ln * 2;                   // feature offset within slice (0..14)
    float di = dinv[node];
    unsigned int sp = *(const unsigned int*)&h[(sbase + node) * 16 + fo];
    float ax0 = di * bflo(sp), ay0 = di * bfhi(sp);
    float ax1 = 0.f, ay1 = 0.f, ax2 = 0.f, ay2 = 0.f, ax3 = 0.f, ay3 = 0.f;
    int s = offs[node], e = offs[node + 1];
    int j = s;
    for (; j + 8 <= e; j += 8) {
        unsigned int v0 = edat[j], v1 = edat[j + 1], v2 = edat[j + 2], v3 = edat[j + 3];
        unsigned int v4 = edat[j + 4], v5 = edat[j + 5], v6 = edat[j + 6], v7 = edat[j + 7];
        unsigned int p0 = *(const unsigned int*)&h[(sbase + (v0 & 0xFFFFu)) * 16 + fo];
        unsigned int p1 = *(const unsigned int*)&h[(sbase + (v1 & 0xFFFFu)) * 16 + fo];
        unsigned int p2 = *(const unsigned int*)&h[(sbase + (v2 & 0xFFFFu)) * 16 + fo];
        unsigned int p3 = *(const unsigned int*)&h[(sbase + (v3 & 0xFFFFu)) * 16 + fo];
        unsigned int p4 = *(const unsigned int*)&h[(sbase + (v4 & 0xFFFFu)) * 16 + fo];
        unsigned int p5 = *(const unsigned int*)&h[(sbase + (v5 & 0xFFFFu)) * 16 + fo];
        unsigned int p6 = *(const unsigned int*)&h[(sbase + (v6 & 0xFFFFu)) * 16 + fo];
        unsigned int p7 = *(const unsigned int*)&h[(sbase + (v7 & 0xFFFFu)) * 16 + fo];
        float w0 = __half2float(__ushort_as_half((unsigned short)(v0 >> 16)));
        float w1 = __half2float(__ushort_as_half((unsigned short)(v1 >> 16)));
        float w2 = __half2float(__ushort_as_half((unsigned short)(v2 >> 16)));
        float w3 = __half2float(__ushort_as_half((unsigned short)(v3 >> 16)));
        float w4 = __half2float(__ushort_as_half((unsigned short)(v4 >> 16)));
        float w5 = __half2float(__ushort_as_half((unsigned short)(v5 >> 16)));
        float w6 = __half2float(__ushort_as_half((unsigned short)(v6 >> 16)));
        float w7 = __half2float(__ushort_as_half((unsigned short)(v7 >> 16)));
        ax0 = fmaf(w0, bflo(p0), ax0); ay0 = fmaf(w0, bfhi(p0), ay0);
        ax1 = fmaf(w1, bflo(p1), ax1); ay1 = fmaf(w1, bfhi(p1), ay1);
        ax2 = fmaf(w2, bflo(p2), ax2); ay2 = fmaf(w2, bfhi(p2), ay2);
        ax3 = fmaf(w3, bflo(p3), ax3); ay3 = fmaf(w3, bfhi(p3), ay3);
        ax0 = fmaf(w4, bflo(p4), ax0); ay0 = fmaf(w4, bfhi(p4), ay0);
        ax1 = fmaf(w5, bflo(p5), ax1); ay1 = fmaf(w5, bfhi(p5), ay1);
        ax2 = fmaf(w6, bflo(p6), ax2); ay2 = fmaf(w6, bfhi(p6), ay2);
        ax3 = fmaf(w7, bflo(p7), ax3); ay3 = fmaf(w7, bfhi(p7), ay3);
    }
    for (; j + 4 <= e; j += 4) {
        unsigned int v0 = edat[j], v1 = edat[j + 1], v2 = edat[j + 2], v3 = edat[j + 3];
        unsigned int p0 = *(const unsigned int*)&h[(sbase + (v0 & 0xFFFFu)) * 16 + fo];
        unsigned int p1 = *(const unsigned int*)&h[(sbase + (v1 & 0xFFFFu)) * 16 + fo];
        unsigned int p2 = *(const unsigned int*)&h[(sbase + (v2 & 0xFFFFu)) * 16 + fo];
        unsigned int p3 = *(const unsigned int*)&h[(sbase + (v3 & 0xFFFFu)) * 16 + fo];
        float w0 = __half2float(__ushort_as_half((unsigned short)(v0 >> 16)));
        float w1 = __half2float(__ushort_as_half((unsigned short)(v1 >> 16)));
        float w2 = __half2float(__ushort_as_half((unsigned short)(v2 >> 16)));
        float w3 = __half2float(__ushort_as_half((unsigned short)(v3 >> 16)));
        ax0 = fmaf(w0, bflo(p0), ax0); ay0 = fmaf(w0, bfhi(p0), ay0);
        ax1 = fmaf(w1, bflo(p1), ax1); ay1 = fmaf(w1, bfhi(p1), ay1);
        ax2 = fmaf(w2, bflo(p2), ax2); ay2 = fmaf(w2, bfhi(p2), ay2);
        ax3 = fmaf(w3, bflo(p3), ax3); ay3 = fmaf(w3, bfhi(p3), ay3);
    }
    for (; j < e; j++) {
        unsigned int v0 = edat[j];
        unsigned int p0 = *(const unsigned int*)&h[(sbase + (v0 & 0xFFFFu)) * 16 + fo];
        float w0 = __half2float(__ushort_as_half((unsigned short)(v0 >> 16)));
        ax0 = fmaf(w0, bflo(p0), ax0);
        ay0 = fmaf(w0, bfhi(p0), ay0);
    }
    float ax = (ax0 + ax1) + (ax2 + ax3);
    float ay = (ay0 + ay1) + (ay2 + ay3);
    int cg = slice * 16 + fo;  // global feature index
    float2 b = *(const float2*)&bias[cg];
    float rx = fmaxf(fmaf(di, ax, b.x), 0.f);
    float ry = fmaxf(fmaf(di, ay, b.y), 0.f);
    if (fout) {
        unsigned long long pv = (unsigned long long)__float_as_uint(rx) |
                                ((unsigned long long)__float_as_uint(ry) << 32);
        __builtin_nontemporal_store(pv, (unsigned long long*)&fout[(size_t)node * GCN_DIM + cg]);
    } else {
        unsigned short hx = f2bf(rx), hy = f2bf(ry);
        unsigned int hp = (unsigned int)hx | ((unsigned int)hy << 16);
        unsigned short lx = f2bf(rx - bf2f(hx)), ly = f2bf(ry - bf2f(hy));
        unsigned int lp = (unsigned int)lx | ((unsigned int)ly << 16);
        __builtin_nontemporal_store(hp, (unsigned int*)&xh_out[(size_t)node * GCN_DIM + cg]);
        __builtin_nontemporal_store(lp, (unsigned int*)&xl_out[(size_t)node * GCN_DIM + cg]);
    }
}

extern "C" void kernel_launch(void* const* d_in, const int* in_sizes, int n_in,
                              void* d_out, int out_size, void* d_ws, size_t ws_size,
                              hipStream_t stream) {
    const float* x0    = (const float*)d_in[0];
    const int*   edges = (const int*)d_in[1];   // [2, E] int32: src then dst
    const float* Wall  = (const float*)d_in[2]; // [L, 128, 128]
    const float* Ball  = (const float*)d_in[3]; // [L, 128]
    float* out = (float*)d_out;

    const int n = in_sizes[0] / GCN_DIM;              // 50000
    const int E = in_sizes[1] / 2;                    // 800000
    const int L = in_sizes[2] / (GCN_DIM * GCN_DIM);  // 5

    // workspace layout
    int*   cnt    = (int*)d_ws;                        // n
    float* dinv   = (float*)(cnt + n);                 // n
    int*   offs   = (int*)(dinv + n);                  // n+16
    int*   bsum   = offs + n + 16;                     // 64
    int*   rank   = bsum + 64;                         // E
    unsigned int* edat = (unsigned int*)(rank + E);    // E (4B each)
    unsigned short* h   = (unsigned short*)(edat + E); // n*128 bf16 (slice-major)
    unsigned short* xh  = h  + (size_t)n * GCN_DIM;    // n*128 bf16
    unsigned short* xl  = xh + (size_t)n * GCN_DIM;    // n*128 bf16
    unsigned short* Wfh = xl + (size_t)n * GCN_DIM;    // L*16384 bf16 frag-order
    unsigned short* Wfl = Wfh + (size_t)L * GCN_DIM * GCN_DIM;

    const int* src = edges;
    const int* dst = edges + E;

    int nb_n = (n + 255) / 256;
    int nb_e = (E + 255) / 256;
    int nb_scan = (n + 1023) / 1024;

    hipMemsetAsync(cnt, 0, (size_t)n * sizeof(int), stream);
    count_kernel<<<nb_e, 256, 0, stream>>>(dst, cnt, rank, E);
    scan_part_kernel<<<nb_scan, 256, 0, stream>>>(cnt, offs, bsum, n);
    scan_top_kernel<<<1, 256, 0, stream>>>(bsum, nb_scan);
    scan_add_kernel<<<nb_n, 256, 0, stream>>>(offs, bsum, cnt, dinv, n, E);
    fill_kernel<<<nb_e, 256, 0, stream>>>(src, dst, dinv, rank, offs, edat, E);

    int xtotal = n * GCN_DIM;
    split_x_kernel<<<(xtotal / 4 + 255) / 256, 256, 0, stream>>>(x0, xh, xl, xtotal);
    int wtotal = L * GCN_DIM * GCN_DIM;
    wsplit_kernel<<<(wtotal + 255) / 256, 256, 0, stream>>>(Wall, Wfh, Wfl, wtotal);

    int gemm_blocks = (n + 63) / 64;
    int agg_blocks  = ((n + 31) / 32) * 8;  // 32 nodes x 8 slices per block

    for (int l = 0; l < L; l++) {
        gemm_mfma_kernel<<<gemm_blocks, 256, 0, stream>>>(
            xh, xl, Wfh + (size_t)l * GCN_DIM * GCN_DIM, Wfl + (size_t)l * GCN_DIM * GCN_DIM, h, n);
        agg_kernel<<<agg_blocks, 256, 0, stream>>>(
            h, edat, offs, dinv, Ball + (size_t)l * GCN_DIM,
            xh, xl, (l == L - 1) ? out : nullptr, n);
    }
}